// Round 6
// baseline (888.373 us; speedup 1.0000x reference)
//
#include <hip/hip_runtime.h>
#include <math.h>

#define Bb 8
#define Ss 2048
#define Ee 256
#define Hh 4
#define Dd 64
#define TC 4            // t-chunks for split-T AV
#define TS (Ss / TC)    // 512

typedef unsigned short u16;
typedef unsigned int u32;
typedef __attribute__((ext_vector_type(8))) short bf16x8;
typedef __attribute__((ext_vector_type(4))) float f32x4;

__device__ __forceinline__ u16 f2bf(float f) {
  union { float f; u32 u; } c; c.f = f;
  return (u16)((c.u + 0x7FFFu + ((c.u >> 16) & 1u)) >> 16);
}
__device__ __forceinline__ float bf2f(u16 u) {
  union { u32 u; float f; } c; c.u = ((u32)u) << 16;
  return c.f;
}
__device__ __forceinline__ float bf2fs(short s) { return bf2f((u16)s); }
__device__ __forceinline__ u32 packbf(float a, float b) {
  return (u32)f2bf(a) | ((u32)f2bf(b) << 16);
}
__device__ __forceinline__ float lo2f(u32 p) {
  union { u32 u; float f; } c; c.u = p << 16; return c.f;
}
__device__ __forceinline__ float hi2f(u32 p) {
  union { u32 u; float f; } c; c.u = p & 0xffff0000u; return c.f;
}

// ---------------- weight fp32 -> bf16 convert ----------------
__global__ __launch_bounds__(256) void k_w2b(const float* __restrict__ src,
                                             u16* __restrict__ dst) {
  int idx = (blockIdx.x * 256 + threadIdx.x) * 4;
  float4 v = *reinterpret_cast<const float4*>(src + idx);
  ushort4 o;
  o.x = f2bf(v.x); o.y = f2bf(v.y); o.z = f2bf(v.z); o.w = f2bf(v.w);
  *reinterpret_cast<ushort4*>(dst + idx) = o;
}

// ---------------- embedding gather (fp32 x + bf16 xb) ----------------
__global__ __launch_bounds__(256) void k_gather(const int* __restrict__ seqs,
                                                const float* __restrict__ emb,
                                                float* __restrict__ x,
                                                u16* __restrict__ xb) {
  int idx = blockIdx.x * 256 + threadIdx.x;
  int row = idx >> 6, c4 = idx & 63;
  int tok = seqs[row];
  float4 v = reinterpret_cast<const float4*>(emb)[(size_t)tok * 64 + c4];
  reinterpret_cast<float4*>(x)[(size_t)row * 64 + c4] = v;
  ushort4 o;
  o.x = f2bf(v.x); o.y = f2bf(v.y); o.z = f2bf(v.z); o.w = f2bf(v.w);
  reinterpret_cast<ushort4*>(xb)[(size_t)row * 64 + c4] = o;
}

// ---------------- QKV projection (MFMA bf16): relu(xb@W^T+b) -> bf16 --------
__global__ __launch_bounds__(256) void k_qkvm(const u16* __restrict__ xb,
    const u16* __restrict__ Wqb, const u16* __restrict__ Wkb, const u16* __restrict__ Wvb,
    const float* __restrict__ bq, const float* __restrict__ bk, const float* __restrict__ bv,
    u16* __restrict__ Qf, u16* __restrict__ Kf, u16* __restrict__ Vf, int mod) {
  __shared__ short Xs[128][72];
  __shared__ short Ws[128][72];
  int tid = threadIdx.x;
  int bn = blockIdx.x;
  int arr = bn >> 1, coff = (bn & 1) << 7;
  const u16* W = (arr == 0 ? Wqb : arr == 1 ? Wkb : Wvb) + (size_t)mod * 256 * 256;
  const float* bias = (arr == 0 ? bq : arr == 1 ? bk : bv) + mod * 256;
  u16* Out = (arr == 0 ? Qf : arr == 1 ? Kf : Vf);
  int s0 = blockIdx.y * 128;
  int lr = tid >> 1, lc = (tid & 1) << 5;
  int w = tid >> 6, lane = tid & 63, ml = lane & 15, q = lane >> 4;
  int sh = (w >> 1) << 6, th = (w & 1) << 6;
  f32x4 acc[4][4] = {};
  for (int k0 = 0; k0 < 256; k0 += 64) {
#pragma unroll
    for (int hh = 0; hh < 4; hh++) {
      *reinterpret_cast<bf16x8*>(&Xs[lr][lc + hh * 8]) =
          *reinterpret_cast<const bf16x8*>(xb + (size_t)(s0 + lr) * Ee + k0 + lc + hh * 8);
      *reinterpret_cast<bf16x8*>(&Ws[lr][lc + hh * 8]) =
          *reinterpret_cast<const bf16x8*>(W + (size_t)(coff + lr) * Ee + k0 + lc + hh * 8);
    }
    __syncthreads();
#pragma unroll
    for (int ks = 0; ks < 2; ks++) {
      bf16x8 af[4], bfr[4];
#pragma unroll
      for (int mt = 0; mt < 4; mt++)
        af[mt] = *reinterpret_cast<const bf16x8*>(&Xs[sh + mt * 16 + ml][ks * 32 + q * 8]);
#pragma unroll
      for (int nt = 0; nt < 4; nt++)
        bfr[nt] = *reinterpret_cast<const bf16x8*>(&Ws[th + nt * 16 + ml][ks * 32 + q * 8]);
#pragma unroll
      for (int mt = 0; mt < 4; mt++)
#pragma unroll
        for (int nt = 0; nt < 4; nt++)
          acc[mt][nt] = __builtin_amdgcn_mfma_f32_16x16x32_bf16(af[mt], bfr[nt], acc[mt][nt], 0, 0, 0);
    }
    __syncthreads();
  }
#pragma unroll
  for (int mt = 0; mt < 4; mt++)
#pragma unroll
    for (int nt = 0; nt < 4; nt++)
#pragma unroll
      for (int r = 0; r < 4; r++) {
        int gm = s0 + sh + mt * 16 + q * 4 + r;
        int cc = coff + th + nt * 16 + ml;
        float v = acc[mt][nt][r] + bias[cc];
        Out[(size_t)gm * Ee + cc] = f2bf(v > 0.f ? v : 0.f);
      }
}

// ---------------- V transpose: Vf[b][t][h*64+d] -> Vt[(b*4+h)*64+d][t] -------
__global__ __launch_bounds__(256) void k_vt(const u16* __restrict__ Vf,
                                            u16* __restrict__ Vt) {
  __shared__ u16 T[64][72];
  int tid = threadIdx.x;
  int t0 = blockIdx.x * 64;
  int z = blockIdx.y;
  int b = z >> 2, h = z & 3;
  int lr = tid >> 2, lc = (tid & 3) << 4;
#pragma unroll
  for (int hh = 0; hh < 2; hh++) {
    bf16x8 v = *reinterpret_cast<const bf16x8*>(
        Vf + (size_t)(b * Ss + t0 + lr) * Ee + h * Dd + lc + hh * 8);
#pragma unroll
    for (int j = 0; j < 8; j++) T[lr][lc + hh * 8 + j] = (u16)v[j];
  }
  __syncthreads();
#pragma unroll
  for (int j = 0; j < 16; j++) {
    Vt[((size_t)z * Dd + lr) * Ss + t0 + lc + j] = T[lc + j][lr];
  }
}

// ---------------- SV[z][d] = sum_t Vt[z*64+d][t] -----------------------------
__global__ __launch_bounds__(256) void k_vsum(const u16* __restrict__ Vt,
                                              float* __restrict__ SV) {
  int z = blockIdx.y;
  int d = blockIdx.x * 4 + (threadIdx.x >> 6);
  int lane = threadIdx.x & 63;
  const u16* row = Vt + ((size_t)z * Dd + d) * Ss;
  float s = 0.f;
#pragma unroll
  for (int it = 0; it < 4; it++) {
    bf16x8 v = *reinterpret_cast<const bf16x8*>(row + it * 512 + lane * 8);
#pragma unroll
    for (int j = 0; j < 8; j++) s += bf2fs(v[j]);
  }
#pragma unroll
  for (int off = 32; off; off >>= 1) s += __shfl_xor(s, off);
  if (lane == 0) SV[(size_t)z * Dd + d] = s;
}

// ---------------- scores (MFMA bf16) + fused column exp-sums -----------------
// block: 128x128 tile; grid (16, 16, nz). Writes Sc (via LDS transpose, 16B
// coalesced) + pl partial column sums (no max: |S| << 1, exact).
__global__ __launch_bounds__(256) void k_scores(const u16* __restrict__ Qf,
    const u16* __restrict__ Kf, u16* __restrict__ Sc,
    float* __restrict__ pl, int bStart) {
  __shared__ short lds[18432];   // Qs[128][72] | Ks[128][72] -> reused T[128][140]
  __shared__ float sml[4][64];
  short* Qs = lds;
  short* Ks = lds + 9216;
  int tid = threadIdx.x;
  int z = blockIdx.z;
  int b = bStart + (z >> 2), h = z & 3;
  const u16* Qb = Qf + (size_t)b * Ss * Ee + h * Dd;
  const u16* Kb = Kf + (size_t)b * Ss * Ee + h * Dd;
  u16* S = Sc + (size_t)z * Ss * Ss;
  int s0 = blockIdx.y * 128, t0 = blockIdx.x * 128;
  int lr = tid >> 1, lc = (tid & 1) << 5;
#pragma unroll
  for (int hh = 0; hh < 4; hh++) {
    *reinterpret_cast<bf16x8*>(&Qs[lr * 72 + lc + hh * 8]) =
        *reinterpret_cast<const bf16x8*>(Qb + (size_t)(s0 + lr) * Ee + lc + hh * 8);
    *reinterpret_cast<bf16x8*>(&Ks[lr * 72 + lc + hh * 8]) =
        *reinterpret_cast<const bf16x8*>(Kb + (size_t)(t0 + lr) * Ee + lc + hh * 8);
  }
  __syncthreads();
  int w = tid >> 6, lane = tid & 63;
  int ml = lane & 15, q = lane >> 4;
  int sh = (w >> 1) << 6, th = (w & 1) << 6;
  f32x4 acc[4][4] = {};
#pragma unroll
  for (int ks = 0; ks < 2; ks++) {
    bf16x8 af[4], bf[4];
#pragma unroll
    for (int mt = 0; mt < 4; mt++)
      af[mt] = *reinterpret_cast<const bf16x8*>(&Qs[(sh + mt * 16 + ml) * 72 + ks * 32 + q * 8]);
#pragma unroll
    for (int nt = 0; nt < 4; nt++)
      bf[nt] = *reinterpret_cast<const bf16x8*>(&Ks[(th + nt * 16 + ml) * 72 + ks * 32 + q * 8]);
#pragma unroll
    for (int mt = 0; mt < 4; mt++)
#pragma unroll
      for (int nt = 0; nt < 4; nt++)
        acc[mt][nt] = __builtin_amdgcn_mfma_f32_16x16x32_bf16(af[mt], bf[nt], acc[mt][nt], 0, 0, 0);
  }
  // quantize (packed pairs) + per-column exp-sum partials
  u32 qp[4][4][2];
#pragma unroll
  for (int mt = 0; mt < 4; mt++)
#pragma unroll
    for (int nt = 0; nt < 4; nt++) {
      qp[mt][nt][0] = packbf(acc[mt][nt][0] * (1.f / 16.f), acc[mt][nt][1] * (1.f / 16.f));
      qp[mt][nt][1] = packbf(acc[mt][nt][2] * (1.f / 16.f), acc[mt][nt][3] * (1.f / 16.f));
    }
#pragma unroll
  for (int nt = 0; nt < 4; nt++) {
    float csum = 0.f;
#pragma unroll
    for (int mt = 0; mt < 4; mt++) {
      csum += __expf(lo2f(qp[mt][nt][0])) + __expf(hi2f(qp[mt][nt][0]));
      csum += __expf(lo2f(qp[mt][nt][1])) + __expf(hi2f(qp[mt][nt][1]));
    }
    csum += __shfl_xor(csum, 16);
    csum += __shfl_xor(csum, 32);
    sml[w][nt * 16 + ml] = csum;
  }
  __syncthreads();
  // transpose through LDS: T[row][col], row stride 140 (breaks bank conflicts)
  short* T = lds;
#pragma unroll
  for (int mt = 0; mt < 4; mt++)
#pragma unroll
    for (int nt = 0; nt < 4; nt++) {
      int row = sh + mt * 16 + q * 4;
      int col = th + nt * 16 + ml;
      T[(row + 0) * 140 + col] = (short)(qp[mt][nt][0] & 0xffff);
      T[(row + 1) * 140 + col] = (short)(qp[mt][nt][0] >> 16);
      T[(row + 2) * 140 + col] = (short)(qp[mt][nt][1] & 0xffff);
      T[(row + 3) * 140 + col] = (short)(qp[mt][nt][1] >> 16);
    }
  if (tid < 128) {
    int half = tid >> 6, col = tid & 63;
    float l = sml[half][col] + sml[half + 2][col];
    pl[((size_t)z * 16 + blockIdx.y) * Ss + t0 + (half << 6) + col] = l;
  }
  __syncthreads();
  int orow = tid >> 1, oc = (tid & 1) << 6;
#pragma unroll
  for (int k8 = 0; k8 < 8; k8++) {
    bf16x8 v = *reinterpret_cast<const bf16x8*>(&T[orow * 140 + oc + k8 * 8]);
    *reinterpret_cast<bf16x8*>(S + (size_t)(s0 + orow) * Ss + t0 + oc + k8 * 8) = v;
  }
}

// ---------------- column sums combine: icl = 1/sum ---------------------------
__global__ __launch_bounds__(256) void k_colstat2(const float* __restrict__ pl,
    float* __restrict__ icl) {
  int idx = blockIdx.x * 256 + threadIdx.x;  // nz*Ss
  int z = idx >> 11, t = idx & 2047;
  float l = 0.f;
#pragma unroll
  for (int rc = 0; rc < 16; rc++) l += pl[((size_t)z * 16 + rc) * Ss + t];
  icl[(size_t)z * Ss + t] = 1.f / l;
}

// ---------------- AV (MFMA bf16), LDS-free, barrier-free ---------------------
// A1 = exp(S)*icl in (0,1]; A2' = expm1(A1) via poly (A1 bounded by softmax).
// Each wave: 16 rows x 64 d over a TS k-range, fragments loaded direct from
// global (A-frag and B-frag are contiguous bf16x8 in Sc / Vt layouts).
// grid (32, TC, nz), 4 waves/block.
__global__ __launch_bounds__(256) void k_avp(const u16* __restrict__ Sc,
    const u16* __restrict__ Vt, const float* __restrict__ icl,
    float* __restrict__ Opart, float* __restrict__ rspart, int bStart, int nz) {
  int tid = threadIdx.x;
  int w = tid >> 6, lane = tid & 63, ml = lane & 15, q = lane >> 4;
  int z = blockIdx.z, tc = blockIdx.y;
  int zg = bStart * Hh + z;
  const u16* A = Sc + (size_t)z * Ss * Ss;
  const u16* VtZ = Vt + (size_t)zg * Dd * Ss;
  const float* iclz = icl + (size_t)z * Ss;
  int s0 = blockIdx.x * 64 + w * 16;         // this wave's 16-row tile
  const u16* Arow = A + (size_t)(s0 + ml) * Ss + tc * TS;
  f32x4 acc[4] = {};
  float rsum = 0.f;
  for (int k = 0; k < TS; k += 32) {
    int tcol = tc * TS + k + q * 8;
    bf16x8 a = *reinterpret_cast<const bf16x8*>(Arow + k + q * 8);
    float4 i0 = *reinterpret_cast<const float4*>(iclz + tcol);
    float4 i1 = *reinterpret_cast<const float4*>(iclz + tcol + 4);
    float iv[8] = {i0.x, i0.y, i0.z, i0.w, i1.x, i1.y, i1.z, i1.w};
    bf16x8 af;
#pragma unroll
    for (int j = 0; j < 8; j++) {
      float e1 = __expf(bf2fs(a[j])) * iv[j];          // A1 in (0,1]
      float p = e1 * (1.f + e1 * (0.5f + e1 * (0.166666667f +
                e1 * (0.0416666667f + e1 * 0.00833333333f))));  // expm1
      rsum += p;
      af[j] = (short)f2bf(p);
    }
#pragma unroll
    for (int nt = 0; nt < 4; nt++) {
      bf16x8 bv = *reinterpret_cast<const bf16x8*>(VtZ + (size_t)(nt * 16 + ml) * Ss + tcol);
      acc[nt] = __builtin_amdgcn_mfma_f32_16x16x32_bf16(af, bv, acc[nt], 0, 0, 0);
    }
  }
  rsum += __shfl_xor(rsum, 16);
  rsum += __shfl_xor(rsum, 32);
  size_t pbase = (size_t)(tc * nz + z) * Ss;
  if (lane < 16) rspart[pbase + s0 + ml] = rsum;
#pragma unroll
  for (int nt = 0; nt < 4; nt++)
#pragma unroll
    for (int r = 0; r < 4; r++)
      Opart[(pbase + s0 + q * 4 + r) * Dd + nt * 16 + ml] = acc[nt][r];
}

// ---------------- combine split-T partials + SV, normalize, write Zb bf16 ----
__global__ __launch_bounds__(256) void k_avred(const float* __restrict__ Opart,
    const float* __restrict__ rspart, const float* __restrict__ SV,
    u16* __restrict__ Zb, int bStart, int nz) {
  int e = blockIdx.x * 256 + threadIdx.x;    // nz*Ss*16 float4s
  int z = e >> 15, s = (e >> 4) & 2047, d4 = e & 15;
  int zg = bStart * Hh + z;
  float4 sv = *reinterpret_cast<const float4*>(SV + (size_t)zg * Dd + d4 * 4);
  float4 o = sv;
  float rs = (float)Ss;
#pragma unroll
  for (int tc = 0; tc < TC; tc++) {
    const float4* P = reinterpret_cast<const float4*>(
        Opart + ((size_t)(tc * nz + z) * Ss + s) * Dd);
    float4 p = P[d4];
    o.x += p.x; o.y += p.y; o.z += p.z; o.w += p.w;
    rs += rspart[(size_t)(tc * nz + z) * Ss + s];
  }
  float inv = 1.f / rs;
  int b = bStart + (z >> 2), h = z & 3;
  ushort4 r;
  r.x = f2bf(o.x * inv); r.y = f2bf(o.y * inv);
  r.z = f2bf(o.z * inv); r.w = f2bf(o.w * inv);
  *reinterpret_cast<ushort4*>(Zb + (size_t)(b * Ss + s) * Ee + h * Dd + d4 * 4) = r;
}

// ---------------- ZF (MFMA bf16) + residual: x += Zb@Wz^T + bz; xb refresh ---
__global__ __launch_bounds__(256) void k_zfm(const u16* __restrict__ Zb,
    const u16* __restrict__ Wzb, const float* __restrict__ bzp,
    float* __restrict__ x, u16* __restrict__ xb, int mod) {
  __shared__ short Zs[128][72];
  __shared__ short Ws[128][72];
  int tid = threadIdx.x;
  int coff = blockIdx.x << 7;
  const u16* W = Wzb + (size_t)mod * 256 * 256;
  const float* bias = bzp + mod * Ee;
  int s0 = blockIdx.y * 128;
  int lr = tid >> 1, lc = (tid & 1) << 5;
  int w = tid >> 6, lane = tid & 63, ml = lane & 15, q = lane >> 4;
  int sh = (w >> 1) << 6, th = (w & 1) << 6;
  f32x4 acc[4][4] = {};
  for (int k0 = 0; k0 < 256; k0 += 64) {
#pragma unroll
    for (int hh = 0; hh < 4; hh++) {
      *reinterpret_cast<bf16x8*>(&Zs[lr][lc + hh * 8]) =
          *reinterpret_cast<const bf16x8*>(Zb + (size_t)(s0 + lr) * Ee + k0 + lc + hh * 8);
      *reinterpret_cast<bf16x8*>(&Ws[lr][lc + hh * 8]) =
          *reinterpret_cast<const bf16x8*>(W + (size_t)(coff + lr) * Ee + k0 + lc + hh * 8);
    }
    __syncthreads();
#pragma unroll
    for (int ks = 0; ks < 2; ks++) {
      bf16x8 af[4], bfr[4];
#pragma unroll
      for (int mt = 0; mt < 4; mt++)
        af[mt] = *reinterpret_cast<const bf16x8*>(&Zs[sh + mt * 16 + ml][ks * 32 + q * 8]);
#pragma unroll
      for (int nt = 0; nt < 4; nt++)
        bfr[nt] = *reinterpret_cast<const bf16x8*>(&Ws[th + nt * 16 + ml][ks * 32 + q * 8]);
#pragma unroll
      for (int mt = 0; mt < 4; mt++)
#pragma unroll
        for (int nt = 0; nt < 4; nt++)
          acc[mt][nt] = __builtin_amdgcn_mfma_f32_16x16x32_bf16(af[mt], bfr[nt], acc[mt][nt], 0, 0, 0);
    }
    __syncthreads();
  }
#pragma unroll
  for (int mt = 0; mt < 4; mt++)
#pragma unroll
    for (int nt = 0; nt < 4; nt++)
#pragma unroll
      for (int r = 0; r < 4; r++) {
        int gm = s0 + sh + mt * 16 + q * 4 + r;
        int gn = coff + th + nt * 16 + ml;
        float xv = x[(size_t)gm * Ee + gn] + acc[mt][nt][r] + bias[gn];
        x[(size_t)gm * Ee + gn] = xv;
        xb[(size_t)gm * Ee + gn] = f2bf(xv);
      }
}

// ---------------- final head ----------------
__global__ __launch_bounds__(256) void k_final1(const float* __restrict__ x,
    const float* __restrict__ Wo, float* __restrict__ part) {
  int c = blockIdx.x, l = blockIdx.y, b = blockIdx.z;
  int tid = threadIdx.x;
  const float4* xr = reinterpret_cast<const float4*>(x + (size_t)b * (Ss * Ee) + c * 8192);
  const float4* wr = reinterpret_cast<const float4*>(Wo + (size_t)l * (Ss * Ee) + c * 8192);
  float sum = 0.f;
  for (int i = tid; i < 2048; i += 256) {
    float4 a = xr[i], w = wr[i];
    sum += a.x * w.x + a.y * w.y + a.z * w.z + a.w * w.w;
  }
  __shared__ float red[256];
  red[tid] = sum;
  __syncthreads();
  for (int o = 128; o; o >>= 1) {
    if (tid < o) red[tid] += red[tid + o];
    __syncthreads();
  }
  if (tid == 0) part[((b * 16 + l) << 6) + c] = red[0];
}

__global__ void k_final2(const float* __restrict__ part, const float* __restrict__ bo,
                         float* __restrict__ out) {
  int idx = threadIdx.x;   // 128 = 8*16
  int b = idx >> 4, l = idx & 15;
  float s = 0.f;
  for (int c = 0; c < 64; c++) s += part[((b * 16 + l) << 6) + c];
  s += bo[l];
  out[idx] = 1.f / (1.f + __expf(-s));
}

extern "C" void kernel_launch(void* const* d_in, const int* in_sizes, int n_in,
                              void* d_out, int out_size, void* d_ws, size_t ws_size,
                              hipStream_t stream) {
  const int*   seqs = (const int*)d_in[0];
  const float* emb  = (const float*)d_in[1];
  const float* Wq   = (const float*)d_in[2];
  const float* bq   = (const float*)d_in[3];
  const float* Wk   = (const float*)d_in[4];
  const float* bk   = (const float*)d_in[5];
  const float* Wv   = (const float*)d_in[6];
  const float* bv   = (const float*)d_in[7];
  const float* Wz   = (const float*)d_in[8];
  const float* bz   = (const float*)d_in[9];
  const float* Wo   = (const float*)d_in[10];
  const float* bo   = (const float*)d_in[11];
  float* out = (float*)d_out;
  float* ws  = (float*)d_ws;

  float* x    = ws;                                    // 4,194,304 f
  u16*   xb   = (u16*)(ws + 4194304);
  u16*   Qf   = (u16*)(ws + 6291456);
  u16*   Kf   = (u16*)(ws + 8388608);
  u16*   Vf   = (u16*)(ws + 10485760);
  u16*   Vt   = (u16*)(ws + 12582912);
  u16*   Zb   = (u16*)(ws + 14680064);
  float* SV   = ws + 16777216;                         // 2,048 f
  float* part = ws + 16779264;                         // 8,192 f
  u16*   Wqb  = (u16*)(ws + 16787456);
  u16*   Wkb  = (u16*)(ws + 16852992);
  u16*   Wvb  = (u16*)(ws + 16918528);
  u16*   Wzb  = (u16*)(ws + 16984064);
  size_t base = 17049600;

  // chunk region per statN: icl 1 + pl 16 + rspart 4 + Opart 256 + Sc 1024
  int CH = 1;
  for (int c = 8; c >= 1; c >>= 1) {
    size_t statN = (size_t)c * Hh * Ss;
    size_t need = base + statN * 1301;
    if (need * 4 <= ws_size) { CH = c; break; }
  }
  size_t statN = (size_t)CH * Hh * Ss;
  float* icl    = ws + base;
  float* pl     = icl + statN;
  float* rspart = pl + statN * 16;
  float* Opart  = rspart + statN * TC;
  u16*   Sc     = (u16*)(Opart + statN * TC * Dd);

  k_gather<<<(Bb * Ss * 64) / 256, 256, 0, stream>>>(seqs, emb, x, xb);
  k_w2b<<<131072 / 1024, 256, 0, stream>>>(Wq, Wqb);
  k_w2b<<<131072 / 1024, 256, 0, stream>>>(Wk, Wkb);
  k_w2b<<<131072 / 1024, 256, 0, stream>>>(Wv, Wvb);
  k_w2b<<<131072 / 1024, 256, 0, stream>>>(Wz, Wzb);

  for (int m = 0; m < 2; m++) {
    k_qkvm<<<dim3(6, 128), 256, 0, stream>>>(xb, Wqb, Wkb, Wvb, bq, bk, bv, Qf, Kf, Vf, m);
    k_vt<<<dim3(32, 32), 256, 0, stream>>>(Vf, Vt);
    k_vsum<<<dim3(16, 32), 256, 0, stream>>>(Vt, SV);
    for (int b0 = 0; b0 < Bb; b0 += CH) {
      int nb = (Bb - b0 < CH) ? (Bb - b0) : CH;
      int nz = nb * Hh;
      k_scores<<<dim3(16, 16, nz), 256, 0, stream>>>(Qf, Kf, Sc, pl, b0);
      k_colstat2<<<(nz * Ss) / 256, 256, 0, stream>>>(pl, icl);
      k_avp<<<dim3(32, TC, nz), 256, 0, stream>>>(Sc, Vt, icl, Opart, rspart, b0, nz);
      k_avred<<<(nz * Ss * 16) / 256, 256, 0, stream>>>(Opart, rspart, SV, Zb, b0, nz);
    }
    k_zfm<<<dim3(2, 128), 256, 0, stream>>>(Zb, Wzb, bz, x, xb, m);
  }

  k_final1<<<dim3(64, 16, 8), 256, 0, stream>>>(x, Wo, part);
  k_final2<<<1, 128, 0, stream>>>(part, bo, out);
}

// Round 7
// 539.092 us; speedup vs baseline: 1.6479x; 1.6479x over previous
//
#include <hip/hip_runtime.h>
#include <math.h>

#define Bb 8
#define Ss 2048
#define Ee 256
#define Hh 4
#define Dd 64

typedef unsigned short u16;
typedef unsigned int u32;
typedef __attribute__((ext_vector_type(8))) short bf16x8;
typedef __attribute__((ext_vector_type(4))) float f32x4;

__device__ __forceinline__ u16 f2bf(float f) {
  union { float f; u32 u; } c; c.f = f;
  return (u16)((c.u + 0x7FFFu + ((c.u >> 16) & 1u)) >> 16);
}
__device__ __forceinline__ float bf2f(u16 u) {
  union { u32 u; float f; } c; c.u = ((u32)u) << 16;
  return c.f;
}
__device__ __forceinline__ float bf2fs(short s) { return bf2f((u16)s); }

// ---------------- weight fp32 -> bf16 convert ----------------
__global__ __launch_bounds__(256) void k_w2b(const float* __restrict__ src,
                                             u16* __restrict__ dst) {
  int idx = (blockIdx.x * 256 + threadIdx.x) * 4;
  float4 v = *reinterpret_cast<const float4*>(src + idx);
  ushort4 o;
  o.x = f2bf(v.x); o.y = f2bf(v.y); o.z = f2bf(v.z); o.w = f2bf(v.w);
  *reinterpret_cast<ushort4*>(dst + idx) = o;
}

// ---------------- embedding gather (fp32 x + bf16 xb) ----------------
__global__ __launch_bounds__(256) void k_gather(const int* __restrict__ seqs,
                                                const float* __restrict__ emb,
                                                float* __restrict__ x,
                                                u16* __restrict__ xb) {
  int idx = blockIdx.x * 256 + threadIdx.x;
  int row = idx >> 6, c4 = idx & 63;
  int tok = seqs[row];
  float4 v = reinterpret_cast<const float4*>(emb)[(size_t)tok * 64 + c4];
  reinterpret_cast<float4*>(x)[(size_t)row * 64 + c4] = v;
  ushort4 o;
  o.x = f2bf(v.x); o.y = f2bf(v.y); o.z = f2bf(v.z); o.w = f2bf(v.w);
  reinterpret_cast<ushort4*>(xb)[(size_t)row * 64 + c4] = o;
}

// ---------------- QKV projection (MFMA bf16): relu(xb@W^T+b) -> bf16 --------
__global__ __launch_bounds__(256) void k_qkvm(const u16* __restrict__ xb,
    const u16* __restrict__ Wqb, const u16* __restrict__ Wkb, const u16* __restrict__ Wvb,
    const float* __restrict__ bq, const float* __restrict__ bk, const float* __restrict__ bv,
    u16* __restrict__ Qf, u16* __restrict__ Kf, u16* __restrict__ Vf, int mod) {
  __shared__ short Xs[128][72];
  __shared__ short Ws[128][72];
  int tid = threadIdx.x;
  int bn = blockIdx.x;
  int arr = bn >> 1, coff = (bn & 1) << 7;
  const u16* W = (arr == 0 ? Wqb : arr == 1 ? Wkb : Wvb) + (size_t)mod * 256 * 256;
  const float* bias = (arr == 0 ? bq : arr == 1 ? bk : bv) + mod * 256;
  u16* Out = (arr == 0 ? Qf : arr == 1 ? Kf : Vf);
  int s0 = blockIdx.y * 128;
  int lr = tid >> 1, lc = (tid & 1) << 5;
  int w = tid >> 6, lane = tid & 63, ml = lane & 15, q = lane >> 4;
  int sh = (w >> 1) << 6, th = (w & 1) << 6;
  f32x4 acc[4][4] = {};
  for (int k0 = 0; k0 < 256; k0 += 64) {
#pragma unroll
    for (int hh = 0; hh < 4; hh++) {
      *reinterpret_cast<bf16x8*>(&Xs[lr][lc + hh * 8]) =
          *reinterpret_cast<const bf16x8*>(xb + (size_t)(s0 + lr) * Ee + k0 + lc + hh * 8);
      *reinterpret_cast<bf16x8*>(&Ws[lr][lc + hh * 8]) =
          *reinterpret_cast<const bf16x8*>(W + (size_t)(coff + lr) * Ee + k0 + lc + hh * 8);
    }
    __syncthreads();
#pragma unroll
    for (int ks = 0; ks < 2; ks++) {
      bf16x8 af[4], bfr[4];
#pragma unroll
      for (int mt = 0; mt < 4; mt++)
        af[mt] = *reinterpret_cast<const bf16x8*>(&Xs[sh + mt * 16 + ml][ks * 32 + q * 8]);
#pragma unroll
      for (int nt = 0; nt < 4; nt++)
        bfr[nt] = *reinterpret_cast<const bf16x8*>(&Ws[th + nt * 16 + ml][ks * 32 + q * 8]);
#pragma unroll
      for (int mt = 0; mt < 4; mt++)
#pragma unroll
        for (int nt = 0; nt < 4; nt++)
          acc[mt][nt] = __builtin_amdgcn_mfma_f32_16x16x32_bf16(af[mt], bfr[nt], acc[mt][nt], 0, 0, 0);
    }
    __syncthreads();
  }
#pragma unroll
  for (int mt = 0; mt < 4; mt++)
#pragma unroll
    for (int nt = 0; nt < 4; nt++)
#pragma unroll
      for (int r = 0; r < 4; r++) {
        int gm = s0 + sh + mt * 16 + q * 4 + r;
        int cc = coff + th + nt * 16 + ml;
        float v = acc[mt][nt][r] + bias[cc];
        Out[(size_t)gm * Ee + cc] = f2bf(v > 0.f ? v : 0.f);
      }
}

// ---------------- V transpose: Vf[b][t][h*64+d] -> Vt[(b*4+h)*64+d][t] -------
__global__ __launch_bounds__(256) void k_vt(const u16* __restrict__ Vf,
                                            u16* __restrict__ Vt) {
  __shared__ u16 T[64][72];
  int tid = threadIdx.x;
  int t0 = blockIdx.x * 64;
  int z = blockIdx.y;
  int b = z >> 2, h = z & 3;
  int lr = tid >> 2, lc = (tid & 3) << 4;
#pragma unroll
  for (int hh = 0; hh < 2; hh++) {
    bf16x8 v = *reinterpret_cast<const bf16x8*>(
        Vf + (size_t)(b * Ss + t0 + lr) * Ee + h * Dd + lc + hh * 8);
#pragma unroll
    for (int j = 0; j < 8; j++) T[lr][lc + hh * 8 + j] = (u16)v[j];
  }
  __syncthreads();
#pragma unroll
  for (int j = 0; j < 16; j++) {
    Vt[((size_t)z * Dd + lr) * Ss + t0 + lc + j] = T[lc + j][lr];
  }
}

// ---------------- SV[z][d] = sum_t Vt[z*64+d][t] -----------------------------
__global__ __launch_bounds__(256) void k_vsum(const u16* __restrict__ Vt,
                                              float* __restrict__ SV) {
  int z = blockIdx.y;
  int d = blockIdx.x * 4 + (threadIdx.x >> 6);
  int lane = threadIdx.x & 63;
  const u16* row = Vt + ((size_t)z * Dd + d) * Ss;
  float s = 0.f;
#pragma unroll
  for (int it = 0; it < 4; it++) {
    bf16x8 v = *reinterpret_cast<const bf16x8*>(row + it * 512 + lane * 8);
#pragma unroll
    for (int j = 0; j < 8; j++) s += bf2fs(v[j]);
  }
#pragma unroll
  for (int off = 32; off; off >>= 1) s += __shfl_xor(s, off);
  if (lane == 0) SV[(size_t)z * Dd + d] = s;
}

// ---------------- pass 1: column exp-sums via recomputed S (no Sc store) -----
// grid (16 t-tiles, 32 z). Block owns 128 t-cols, loops all s. icl = 1/colsum.
__global__ __launch_bounds__(256) void k_csum(const u16* __restrict__ Qf,
    const u16* __restrict__ Kf, float* __restrict__ icl) {
  __shared__ short Qs[128 * 72];
  __shared__ short Ks[128 * 72];
  __shared__ float csm[4][64];
  int tid = threadIdx.x;
  int z = blockIdx.y, b = z >> 2, h = z & 3;
  const u16* Qb = Qf + (size_t)b * Ss * Ee + h * Dd;
  const u16* Kb = Kf + (size_t)b * Ss * Ee + h * Dd;
  int t0 = blockIdx.x * 128;
  int lr = tid >> 1, lc = (tid & 1) << 5;
#pragma unroll
  for (int hh = 0; hh < 4; hh++)
    *reinterpret_cast<bf16x8*>(&Ks[lr * 72 + lc + hh * 8]) =
        *reinterpret_cast<const bf16x8*>(Kb + (size_t)(t0 + lr) * Ee + lc + hh * 8);
  int w = tid >> 6, lane = tid & 63, ml = lane & 15, q = lane >> 4;
  int sh = (w >> 1) << 6, th = (w & 1) << 6;
  float csum[4] = {};
  for (int s0 = 0; s0 < Ss; s0 += 128) {
    __syncthreads();
#pragma unroll
    for (int hh = 0; hh < 4; hh++)
      *reinterpret_cast<bf16x8*>(&Qs[lr * 72 + lc + hh * 8]) =
          *reinterpret_cast<const bf16x8*>(Qb + (size_t)(s0 + lr) * Ee + lc + hh * 8);
    __syncthreads();
    f32x4 acc[4][4] = {};
#pragma unroll
    for (int ks = 0; ks < 2; ks++) {
      bf16x8 af[4], bf[4];
#pragma unroll
      for (int mt = 0; mt < 4; mt++)
        af[mt] = *reinterpret_cast<const bf16x8*>(&Qs[(sh + mt * 16 + ml) * 72 + ks * 32 + q * 8]);
#pragma unroll
      for (int nt = 0; nt < 4; nt++)
        bf[nt] = *reinterpret_cast<const bf16x8*>(&Ks[(th + nt * 16 + ml) * 72 + ks * 32 + q * 8]);
#pragma unroll
      for (int mt = 0; mt < 4; mt++)
#pragma unroll
        for (int nt = 0; nt < 4; nt++)
          acc[mt][nt] = __builtin_amdgcn_mfma_f32_16x16x32_bf16(af[mt], bf[nt], acc[mt][nt], 0, 0, 0);
    }
#pragma unroll
    for (int nt = 0; nt < 4; nt++)
#pragma unroll
      for (int mt = 0; mt < 4; mt++)
#pragma unroll
        for (int r = 0; r < 4; r++)
          csum[nt] += __expf(acc[mt][nt][r] * 0.0625f);
  }
#pragma unroll
  for (int nt = 0; nt < 4; nt++) {
    csum[nt] += __shfl_xor(csum[nt], 16);
    csum[nt] += __shfl_xor(csum[nt], 32);
  }
  if (lane < 16) {
#pragma unroll
    for (int nt = 0; nt < 4; nt++) csm[w][nt * 16 + ml] = csum[nt];
  }
  __syncthreads();
  if (tid < 128) {
    int half = tid >> 6, c = tid & 63;
    float l = csm[half][c] + csm[half + 2][c];
    icl[(size_t)z * Ss + t0 + half * 64 + c] = 1.f / l;
  }
}

// ---------------- pass 2: fused attention (recompute S, transform, PV) -------
// grid (16 s-tiles, 32 z). Block owns 128 s-rows, loops all t in 64-chunks:
// QK-MFMA (128x64 tile) -> A1=exp(S)*icl -> A2'=expm1(A1) -> LDS -> PV-MFMA.
// O = (SV + A2'@V) / (2048 + rowsum(A2')), written as bf16 Zb.
__global__ __launch_bounds__(256) void k_att(const u16* __restrict__ Qf,
    const u16* __restrict__ Kf, const u16* __restrict__ Vt,
    const float* __restrict__ icl, const float* __restrict__ SV,
    u16* __restrict__ Zb) {
  __shared__ short Qs[128 * 72];     // 18.4 KB
  __shared__ short Ks[64 * 72];      // 9.2 KB
  __shared__ short Vs[64 * 72];      // 9.2 KB
  __shared__ short A2s[128 * 76];    // 19.5 KB (stride 76 breaks conflicts)
  __shared__ float rs_s[2][128];
  int tid = threadIdx.x;
  int z = blockIdx.y, b = z >> 2, h = z & 3;
  const u16* Qb = Qf + (size_t)b * Ss * Ee + h * Dd;
  const u16* Kb = Kf + (size_t)b * Ss * Ee + h * Dd;
  const u16* VtZ = Vt + (size_t)z * Dd * Ss;
  const float* iclz = icl + (size_t)z * Ss;
  int s0 = blockIdx.x * 128;
  int lr = tid >> 1, lc = (tid & 1) << 5;
#pragma unroll
  for (int hh = 0; hh < 4; hh++)
    *reinterpret_cast<bf16x8*>(&Qs[lr * 72 + lc + hh * 8]) =
        *reinterpret_cast<const bf16x8*>(Qb + (size_t)(s0 + lr) * Ee + lc + hh * 8);
  int w = tid >> 6, lane = tid & 63, ml = lane & 15, q = lane >> 4;
  int ws = (w >> 1) << 6, wt = (w & 1) << 5;
  f32x4 acc2[2][4] = {};
  f32x4 rsv[4] = {};
  for (int t0 = 0; t0 < Ss; t0 += 64) {
    __syncthreads();
    if (tid < 128) {
      int r2 = tid >> 1, h2 = (tid & 1) << 5;
#pragma unroll
      for (int j = 0; j < 4; j++)
        *reinterpret_cast<bf16x8*>(&Ks[r2 * 72 + h2 + j * 8]) =
            *reinterpret_cast<const bf16x8*>(Kb + (size_t)(t0 + r2) * Ee + h2 + j * 8);
    } else {
      int t2 = tid - 128;
      int r2 = t2 >> 1, h2 = (t2 & 1) << 5;
#pragma unroll
      for (int j = 0; j < 4; j++)
        *reinterpret_cast<bf16x8*>(&Vs[r2 * 72 + h2 + j * 8]) =
            *reinterpret_cast<const bf16x8*>(VtZ + (size_t)r2 * Ss + t0 + h2 + j * 8);
    }
    __syncthreads();
    // QK: wave computes 64 s-rows x 32 t-cols
    f32x4 acc[4][2] = {};
#pragma unroll
    for (int ks = 0; ks < 2; ks++) {
      bf16x8 af[4], bf[2];
#pragma unroll
      for (int mt = 0; mt < 4; mt++)
        af[mt] = *reinterpret_cast<const bf16x8*>(&Qs[(ws + mt * 16 + ml) * 72 + ks * 32 + q * 8]);
#pragma unroll
      for (int nt = 0; nt < 2; nt++)
        bf[nt] = *reinterpret_cast<const bf16x8*>(&Ks[(wt + nt * 16 + ml) * 72 + ks * 32 + q * 8]);
#pragma unroll
      for (int mt = 0; mt < 4; mt++)
#pragma unroll
        for (int nt = 0; nt < 2; nt++)
          acc[mt][nt] = __builtin_amdgcn_mfma_f32_16x16x32_bf16(af[mt], bf[nt], acc[mt][nt], 0, 0, 0);
    }
    // transform: A1 = exp(S)*icl in (0,1]; A2' = expm1(A1) poly; stash to LDS
#pragma unroll
    for (int nt = 0; nt < 2; nt++) {
      float ic = iclz[t0 + wt + nt * 16 + ml];
#pragma unroll
      for (int mt = 0; mt < 4; mt++)
#pragma unroll
        for (int r = 0; r < 4; r++) {
          float e1 = __expf(acc[mt][nt][r] * 0.0625f) * ic;
          float p = e1 * (1.f + e1 * (0.5f + e1 * (0.166666667f +
                    e1 * (0.0416666667f + e1 * 0.00833333333f))));
          rsv[mt][r] += p;
          A2s[(ws + mt * 16 + q * 4 + r) * 76 + wt + nt * 16 + ml] = (short)f2bf(p);
        }
    }
    __syncthreads();
    // PV: wave owns 32 s-rows x 64 d
#pragma unroll
    for (int ks = 0; ks < 2; ks++) {
      bf16x8 af2[2], bv[4];
#pragma unroll
      for (int mt2 = 0; mt2 < 2; mt2++)
        af2[mt2] = *reinterpret_cast<const bf16x8*>(&A2s[(w * 32 + mt2 * 16 + ml) * 76 + ks * 32 + q * 8]);
#pragma unroll
      for (int nt = 0; nt < 4; nt++)
        bv[nt] = *reinterpret_cast<const bf16x8*>(&Vs[(nt * 16 + ml) * 72 + ks * 32 + q * 8]);
#pragma unroll
      for (int mt2 = 0; mt2 < 2; mt2++)
#pragma unroll
        for (int nt = 0; nt < 4; nt++)
          acc2[mt2][nt] = __builtin_amdgcn_mfma_f32_16x16x32_bf16(af2[mt2], bv[nt], acc2[mt2][nt], 0, 0, 0);
    }
  }
  // row sums: reduce over the 16 col-lanes, publish per t-half
#pragma unroll
  for (int mt = 0; mt < 4; mt++)
#pragma unroll
    for (int r = 0; r < 4; r++) {
      float v = rsv[mt][r];
      v += __shfl_xor(v, 1); v += __shfl_xor(v, 2);
      v += __shfl_xor(v, 4); v += __shfl_xor(v, 8);
      if (ml == 0) rs_s[w & 1][ws + mt * 16 + q * 4 + r] = v;
    }
  __syncthreads();
  const float* SVz = SV + (size_t)z * Dd;
#pragma unroll
  for (int mt2 = 0; mt2 < 2; mt2++)
#pragma unroll
    for (int r = 0; r < 4; r++) {
      int row = w * 32 + mt2 * 16 + q * 4 + r;
      float inv = 1.f / (2048.f + rs_s[0][row] + rs_s[1][row]);
#pragma unroll
      for (int nt = 0; nt < 4; nt++) {
        float o = (SVz[nt * 16 + ml] + acc2[mt2][nt][r]) * inv;
        Zb[(size_t)(b * Ss + s0 + row) * Ee + h * Dd + nt * 16 + ml] = f2bf(o);
      }
    }
}

// ---------------- ZF (MFMA bf16) + residual: x += Zb@Wz^T + bz; xb refresh ---
__global__ __launch_bounds__(256) void k_zfm(const u16* __restrict__ Zb,
    const u16* __restrict__ Wzb, const float* __restrict__ bzp,
    float* __restrict__ x, u16* __restrict__ xb, int mod) {
  __shared__ short Zs[128][72];
  __shared__ short Ws[128][72];
  int tid = threadIdx.x;
  int coff = blockIdx.x << 7;
  const u16* W = Wzb + (size_t)mod * 256 * 256;
  const float* bias = bzp + mod * Ee;
  int s0 = blockIdx.y * 128;
  int lr = tid >> 1, lc = (tid & 1) << 5;
  int w = tid >> 6, lane = tid & 63, ml = lane & 15, q = lane >> 4;
  int sh = (w >> 1) << 6, th = (w & 1) << 6;
  f32x4 acc[4][4] = {};
  for (int k0 = 0; k0 < 256; k0 += 64) {
#pragma unroll
    for (int hh = 0; hh < 4; hh++) {
      *reinterpret_cast<bf16x8*>(&Zs[lr][lc + hh * 8]) =
          *reinterpret_cast<const bf16x8*>(Zb + (size_t)(s0 + lr) * Ee + k0 + lc + hh * 8);
      *reinterpret_cast<bf16x8*>(&Ws[lr][lc + hh * 8]) =
          *reinterpret_cast<const bf16x8*>(W + (size_t)(coff + lr) * Ee + k0 + lc + hh * 8);
    }
    __syncthreads();
#pragma unroll
    for (int ks = 0; ks < 2; ks++) {
      bf16x8 af[4], bfr[4];
#pragma unroll
      for (int mt = 0; mt < 4; mt++)
        af[mt] = *reinterpret_cast<const bf16x8*>(&Zs[sh + mt * 16 + ml][ks * 32 + q * 8]);
#pragma unroll
      for (int nt = 0; nt < 4; nt++)
        bfr[nt] = *reinterpret_cast<const bf16x8*>(&Ws[th + nt * 16 + ml][ks * 32 + q * 8]);
#pragma unroll
      for (int mt = 0; mt < 4; mt++)
#pragma unroll
        for (int nt = 0; nt < 4; nt++)
          acc[mt][nt] = __builtin_amdgcn_mfma_f32_16x16x32_bf16(af[mt], bfr[nt], acc[mt][nt], 0, 0, 0);
    }
    __syncthreads();
  }
#pragma unroll
  for (int mt = 0; mt < 4; mt++)
#pragma unroll
    for (int nt = 0; nt < 4; nt++)
#pragma unroll
      for (int r = 0; r < 4; r++) {
        int gm = s0 + sh + mt * 16 + q * 4 + r;
        int gn = coff + th + nt * 16 + ml;
        float xv = x[(size_t)gm * Ee + gn] + acc[mt][nt][r] + bias[gn];
        x[(size_t)gm * Ee + gn] = xv;
        xb[(size_t)gm * Ee + gn] = f2bf(xv);
      }
}

// ---------------- final head ----------------
__global__ __launch_bounds__(256) void k_final1(const float* __restrict__ x,
    const float* __restrict__ Wo, float* __restrict__ part) {
  int c = blockIdx.x, l = blockIdx.y, b = blockIdx.z;
  int tid = threadIdx.x;
  const float4* xr = reinterpret_cast<const float4*>(x + (size_t)b * (Ss * Ee) + c * 8192);
  const float4* wr = reinterpret_cast<const float4*>(Wo + (size_t)l * (Ss * Ee) + c * 8192);
  float sum = 0.f;
  for (int i = tid; i < 2048; i += 256) {
    float4 a = xr[i], w = wr[i];
    sum += a.x * w.x + a.y * w.y + a.z * w.z + a.w * w.w;
  }
  __shared__ float red[256];
  red[tid] = sum;
  __syncthreads();
  for (int o = 128; o; o >>= 1) {
    if (tid < o) red[tid] += red[tid + o];
    __syncthreads();
  }
  if (tid == 0) part[((b * 16 + l) << 6) + c] = red[0];
}

__global__ void k_final2(const float* __restrict__ part, const float* __restrict__ bo,
                         float* __restrict__ out) {
  int idx = threadIdx.x;   // 128 = 8*16
  int b = idx >> 4, l = idx & 15;
  float s = 0.f;
  for (int c = 0; c < 64; c++) s += part[((b * 16 + l) << 6) + c];
  s += bo[l];
  out[idx] = 1.f / (1.f + __expf(-s));
}

extern "C" void kernel_launch(void* const* d_in, const int* in_sizes, int n_in,
                              void* d_out, int out_size, void* d_ws, size_t ws_size,
                              hipStream_t stream) {
  const int*   seqs = (const int*)d_in[0];
  const float* emb  = (const float*)d_in[1];
  const float* Wq   = (const float*)d_in[2];
  const float* bq   = (const float*)d_in[3];
  const float* Wk   = (const float*)d_in[4];
  const float* bk   = (const float*)d_in[5];
  const float* Wv   = (const float*)d_in[6];
  const float* bv   = (const float*)d_in[7];
  const float* Wz   = (const float*)d_in[8];
  const float* bz   = (const float*)d_in[9];
  const float* Wo   = (const float*)d_in[10];
  const float* bo   = (const float*)d_in[11];
  float* out = (float*)d_out;
  float* ws  = (float*)d_ws;

  float* x    = ws;                                    // 4,194,304 f
  u16*   xb   = (u16*)(ws + 4194304);
  u16*   Qf   = (u16*)(ws + 6291456);
  u16*   Kf   = (u16*)(ws + 8388608);
  u16*   Vf   = (u16*)(ws + 10485760);
  u16*   Vt   = (u16*)(ws + 12582912);
  u16*   Zb   = (u16*)(ws + 14680064);
  float* SV   = ws + 16777216;                         // 2,048 f
  float* part = ws + 16779264;                         // 8,192 f
  u16*   Wqb  = (u16*)(ws + 16787456);
  u16*   Wkb  = (u16*)(ws + 16852992);
  u16*   Wvb  = (u16*)(ws + 16918528);
  u16*   Wzb  = (u16*)(ws + 16984064);
  float* icl  = ws + 17049600;                         // 65,536 f (32 z x 2048)

  k_gather<<<(Bb * Ss * 64) / 256, 256, 0, stream>>>(seqs, emb, x, xb);
  k_w2b<<<131072 / 1024, 256, 0, stream>>>(Wq, Wqb);
  k_w2b<<<131072 / 1024, 256, 0, stream>>>(Wk, Wkb);
  k_w2b<<<131072 / 1024, 256, 0, stream>>>(Wv, Wvb);
  k_w2b<<<131072 / 1024, 256, 0, stream>>>(Wz, Wzb);

  for (int m = 0; m < 2; m++) {
    k_qkvm<<<dim3(6, 128), 256, 0, stream>>>(xb, Wqb, Wkb, Wvb, bq, bk, bv, Qf, Kf, Vf, m);
    k_vt<<<dim3(32, 32), 256, 0, stream>>>(Vf, Vt);
    k_vsum<<<dim3(16, 32), 256, 0, stream>>>(Vt, SV);
    k_csum<<<dim3(16, 32), 256, 0, stream>>>(Qf, Kf, icl);
    k_att<<<dim3(16, 32), 256, 0, stream>>>(Qf, Kf, Vt, icl, SV, Zb);
    k_zfm<<<dim3(2, 128), 256, 0, stream>>>(Zb, Wzb, bz, x, xb, m);
  }

  k_final1<<<dim3(64, 16, 8), 256, 0, stream>>>(x, Wo, part);
  k_final2<<<1, 128, 0, stream>>>(part, bo, out);
}

// Round 8
// 519.761 us; speedup vs baseline: 1.7092x; 1.0372x over previous
//
#include <hip/hip_runtime.h>
#include <math.h>

#define Bb 8
#define Ss 2048
#define Ee 256
#define Hh 4
#define Dd 64

typedef unsigned short u16;
typedef unsigned int u32;
typedef __attribute__((ext_vector_type(8))) short bf16x8;
typedef __attribute__((ext_vector_type(4))) float f32x4;

__device__ __forceinline__ u16 f2bf(float f) {
  union { float f; u32 u; } c; c.f = f;
  return (u16)((c.u + 0x7FFFu + ((c.u >> 16) & 1u)) >> 16);
}
__device__ __forceinline__ float bf2f(u16 u) {
  union { u32 u; float f; } c; c.u = ((u32)u) << 16;
  return c.f;
}
__device__ __forceinline__ float bf2fs(short s) { return bf2f((u16)s); }

// ---------------- weight fp32 -> bf16 convert ----------------
__global__ __launch_bounds__(256) void k_w2b(const float* __restrict__ src,
                                             u16* __restrict__ dst) {
  int idx = (blockIdx.x * 256 + threadIdx.x) * 4;
  float4 v = *reinterpret_cast<const float4*>(src + idx);
  ushort4 o;
  o.x = f2bf(v.x); o.y = f2bf(v.y); o.z = f2bf(v.z); o.w = f2bf(v.w);
  *reinterpret_cast<ushort4*>(dst + idx) = o;
}

// ---------------- embedding gather (fp32 x + bf16 xb) ----------------
__global__ __launch_bounds__(256) void k_gather(const int* __restrict__ seqs,
                                                const float* __restrict__ emb,
                                                float* __restrict__ x,
                                                u16* __restrict__ xb) {
  int idx = blockIdx.x * 256 + threadIdx.x;
  int row = idx >> 6, c4 = idx & 63;
  int tok = seqs[row];
  float4 v = reinterpret_cast<const float4*>(emb)[(size_t)tok * 64 + c4];
  reinterpret_cast<float4*>(x)[(size_t)row * 64 + c4] = v;
  ushort4 o;
  o.x = f2bf(v.x); o.y = f2bf(v.y); o.z = f2bf(v.z); o.w = f2bf(v.w);
  reinterpret_cast<ushort4*>(xb)[(size_t)row * 64 + c4] = o;
}

// ---------------- QKV projection (MFMA bf16): relu(xb@W^T+b) -> bf16 --------
// Q output pre-scaled by 1/16 (folds the attention scale into Qf).
__global__ __launch_bounds__(256) void k_qkvm(const u16* __restrict__ xb,
    const u16* __restrict__ Wqb, const u16* __restrict__ Wkb, const u16* __restrict__ Wvb,
    const float* __restrict__ bq, const float* __restrict__ bk, const float* __restrict__ bv,
    u16* __restrict__ Qf, u16* __restrict__ Kf, u16* __restrict__ Vf, int mod) {
  __shared__ short Xs[128][72];
  __shared__ short Ws[128][72];
  int tid = threadIdx.x;
  int bn = blockIdx.x;
  int arr = bn >> 1, coff = (bn & 1) << 7;
  const u16* W = (arr == 0 ? Wqb : arr == 1 ? Wkb : Wvb) + (size_t)mod * 256 * 256;
  const float* bias = (arr == 0 ? bq : arr == 1 ? bk : bv) + mod * 256;
  u16* Out = (arr == 0 ? Qf : arr == 1 ? Kf : Vf);
  float oscale = (arr == 0) ? 0.0625f : 1.0f;
  int s0 = blockIdx.y * 128;
  int lr = tid >> 1, lc = (tid & 1) << 5;
  int w = tid >> 6, lane = tid & 63, ml = lane & 15, q = lane >> 4;
  int sh = (w >> 1) << 6, th = (w & 1) << 6;
  f32x4 acc[4][4] = {};
  for (int k0 = 0; k0 < 256; k0 += 64) {
#pragma unroll
    for (int hh = 0; hh < 4; hh++) {
      *reinterpret_cast<bf16x8*>(&Xs[lr][lc + hh * 8]) =
          *reinterpret_cast<const bf16x8*>(xb + (size_t)(s0 + lr) * Ee + k0 + lc + hh * 8);
      *reinterpret_cast<bf16x8*>(&Ws[lr][lc + hh * 8]) =
          *reinterpret_cast<const bf16x8*>(W + (size_t)(coff + lr) * Ee + k0 + lc + hh * 8);
    }
    __syncthreads();
#pragma unroll
    for (int ks = 0; ks < 2; ks++) {
      bf16x8 af[4], bfr[4];
#pragma unroll
      for (int mt = 0; mt < 4; mt++)
        af[mt] = *reinterpret_cast<const bf16x8*>(&Xs[sh + mt * 16 + ml][ks * 32 + q * 8]);
#pragma unroll
      for (int nt = 0; nt < 4; nt++)
        bfr[nt] = *reinterpret_cast<const bf16x8*>(&Ws[th + nt * 16 + ml][ks * 32 + q * 8]);
#pragma unroll
      for (int mt = 0; mt < 4; mt++)
#pragma unroll
        for (int nt = 0; nt < 4; nt++)
          acc[mt][nt] = __builtin_amdgcn_mfma_f32_16x16x32_bf16(af[mt], bfr[nt], acc[mt][nt], 0, 0, 0);
    }
    __syncthreads();
  }
#pragma unroll
  for (int mt = 0; mt < 4; mt++)
#pragma unroll
    for (int nt = 0; nt < 4; nt++)
#pragma unroll
      for (int r = 0; r < 4; r++) {
        int gm = s0 + sh + mt * 16 + q * 4 + r;
        int cc = coff + th + nt * 16 + ml;
        float v = acc[mt][nt][r] + bias[cc];
        v = (v > 0.f ? v : 0.f) * oscale;
        Out[(size_t)gm * Ee + cc] = f2bf(v);
      }
}

// ---------------- V transpose: Vf[b][t][h*64+d] -> Vt[(b*4+h)*64+d][t] -------
__global__ __launch_bounds__(256) void k_vt(const u16* __restrict__ Vf,
                                            u16* __restrict__ Vt) {
  __shared__ u16 T[64][72];
  int tid = threadIdx.x;
  int t0 = blockIdx.x * 64;
  int z = blockIdx.y;
  int b = z >> 2, h = z & 3;
  int lr = tid >> 2, lc = (tid & 3) << 4;
#pragma unroll
  for (int hh = 0; hh < 2; hh++) {
    bf16x8 v = *reinterpret_cast<const bf16x8*>(
        Vf + (size_t)(b * Ss + t0 + lr) * Ee + h * Dd + lc + hh * 8);
#pragma unroll
    for (int j = 0; j < 8; j++) T[lr][lc + hh * 8 + j] = (u16)v[j];
  }
  __syncthreads();
#pragma unroll
  for (int j = 0; j < 16; j++) {
    Vt[((size_t)z * Dd + lr) * Ss + t0 + lc + j] = T[lc + j][lr];
  }
}

// ---------------- SV[z][d] = sum_t Vt[z*64+d][t] -----------------------------
__global__ __launch_bounds__(256) void k_vsum(const u16* __restrict__ Vt,
                                              float* __restrict__ SV) {
  int z = blockIdx.y;
  int d = blockIdx.x * 4 + (threadIdx.x >> 6);
  int lane = threadIdx.x & 63;
  const u16* row = Vt + ((size_t)z * Dd + d) * Ss;
  float s = 0.f;
#pragma unroll
  for (int it = 0; it < 4; it++) {
    bf16x8 v = *reinterpret_cast<const bf16x8*>(row + it * 512 + lane * 8);
#pragma unroll
    for (int j = 0; j < 8; j++) s += bf2fs(v[j]);
  }
#pragma unroll
  for (int off = 32; off; off >>= 1) s += __shfl_xor(s, off);
  if (lane == 0) SV[(size_t)z * Dd + d] = s;
}

// ---------------- pass 1: llic[t] = -ln(sum_s exp(S)) (S recomputed) ---------
// grid (16 t-tiles, 32 z). K B-frags in registers; Q double-buffered in LDS.
__global__ __launch_bounds__(256) void k_csum(const u16* __restrict__ Qf,
    const u16* __restrict__ Kf, float* __restrict__ llic) {
  __shared__ short Qs[2][128 * 72];
  __shared__ float csm[4][64];
  int tid = threadIdx.x;
  int z = blockIdx.y, b = z >> 2, h = z & 3;
  const u16* Qb = Qf + (size_t)b * Ss * Ee + h * Dd;
  const u16* Kb = Kf + (size_t)b * Ss * Ee + h * Dd;
  int t0 = blockIdx.x * 128;
  int lr = tid >> 1, lc = (tid & 1) << 5;
  int w = tid >> 6, lane = tid & 63, ml = lane & 15, q = lane >> 4;
  int sh = (w >> 1) << 6, th = (w & 1) << 6;
  // preload K B-frags (loop-invariant)
  bf16x8 kb[2][4];
#pragma unroll
  for (int ks = 0; ks < 2; ks++)
#pragma unroll
    for (int nt = 0; nt < 4; nt++)
      kb[ks][nt] = *reinterpret_cast<const bf16x8*>(
          Kb + (size_t)(t0 + th + nt * 16 + ml) * Ee + ks * 32 + q * 8);
  float csum[4] = {};
  int p = 0;
  for (int s0 = 0; s0 < Ss; s0 += 128) {
#pragma unroll
    for (int hh = 0; hh < 4; hh++)
      *reinterpret_cast<bf16x8*>(&Qs[p][lr * 72 + lc + hh * 8]) =
          *reinterpret_cast<const bf16x8*>(Qb + (size_t)(s0 + lr) * Ee + lc + hh * 8);
    __syncthreads();
    f32x4 acc[4][4] = {};
#pragma unroll
    for (int ks = 0; ks < 2; ks++) {
      bf16x8 af[4];
#pragma unroll
      for (int mt = 0; mt < 4; mt++)
        af[mt] = *reinterpret_cast<const bf16x8*>(&Qs[p][(sh + mt * 16 + ml) * 72 + ks * 32 + q * 8]);
#pragma unroll
      for (int mt = 0; mt < 4; mt++)
#pragma unroll
        for (int nt = 0; nt < 4; nt++)
          acc[mt][nt] = __builtin_amdgcn_mfma_f32_16x16x32_bf16(af[mt], kb[ks][nt], acc[mt][nt], 0, 0, 0);
    }
#pragma unroll
    for (int nt = 0; nt < 4; nt++)
#pragma unroll
      for (int mt = 0; mt < 4; mt++)
#pragma unroll
        for (int r = 0; r < 4; r++)
          csum[nt] += __expf(acc[mt][nt][r]);
    p ^= 1;
  }
#pragma unroll
  for (int nt = 0; nt < 4; nt++) {
    csum[nt] += __shfl_xor(csum[nt], 16);
    csum[nt] += __shfl_xor(csum[nt], 32);
  }
  if (lane < 16) {
#pragma unroll
    for (int nt = 0; nt < 4; nt++) csm[w][nt * 16 + ml] = csum[nt];
  }
  __syncthreads();
  if (tid < 128) {
    int half = tid >> 6, c = tid & 63;
    float l = csm[half][c] + csm[half + 2][c];
    llic[(size_t)z * Ss + t0 + half * 64 + c] = -__logf(l);
  }
}

// ---------------- pass 2: fused attention (recompute S, transform, PV) -------
// grid (16 s-tiles, 32 z). Q A-frags in registers (no Qs LDS). Per 64-t chunk:
// QK-MFMA -> e1=exp(S+llic) -> A2'=expm1-poly -> A2s LDS -> PV-MFMA.
// O = (SV + A2'@V) / (2048 + rowsum(A2')) -> bf16 Zb.
__global__ __launch_bounds__(256) void k_att(const u16* __restrict__ Qf,
    const u16* __restrict__ Kf, const u16* __restrict__ Vt,
    const float* __restrict__ llic, const float* __restrict__ SV,
    u16* __restrict__ Zb) {
  __shared__ short Ks[64 * 72];      // 9.2 KB
  __shared__ short Vs[64 * 72];      // 9.2 KB
  __shared__ short A2s[128 * 76];    // 19.5 KB
  __shared__ float rs_s[2][128];
  int tid = threadIdx.x;
  int z = blockIdx.y, b = z >> 2, h = z & 3;
  const u16* Qb = Qf + (size_t)b * Ss * Ee + h * Dd;
  const u16* Kb = Kf + (size_t)b * Ss * Ee + h * Dd;
  const u16* VtZ = Vt + (size_t)z * Dd * Ss;
  const float* lz = llic + (size_t)z * Ss;
  int s0 = blockIdx.x * 128;
  int w = tid >> 6, lane = tid & 63, ml = lane & 15, q = lane >> 4;
  int wsd = (w >> 1) << 6, wt = (w & 1) << 5;
  // preload Q A-frags (loop-invariant, 32 VGPRs)
  bf16x8 qa[2][4];
#pragma unroll
  for (int ks = 0; ks < 2; ks++)
#pragma unroll
    for (int mt = 0; mt < 4; mt++)
      qa[ks][mt] = *reinterpret_cast<const bf16x8*>(
          Qb + (size_t)(s0 + wsd + mt * 16 + ml) * Ee + ks * 32 + q * 8);
  f32x4 acc2[2][4] = {};
  f32x4 rsv[4] = {};
  for (int t0 = 0; t0 < Ss; t0 += 64) {
    __syncthreads();
    if (tid < 128) {
      int r2 = tid >> 1, h2 = (tid & 1) << 5;
#pragma unroll
      for (int j = 0; j < 4; j++)
        *reinterpret_cast<bf16x8*>(&Ks[r2 * 72 + h2 + j * 8]) =
            *reinterpret_cast<const bf16x8*>(Kb + (size_t)(t0 + r2) * Ee + h2 + j * 8);
    } else {
      int t2 = tid - 128;
      int r2 = t2 >> 1, h2 = (t2 & 1) << 5;
#pragma unroll
      for (int j = 0; j < 4; j++)
        *reinterpret_cast<bf16x8*>(&Vs[r2 * 72 + h2 + j * 8]) =
            *reinterpret_cast<const bf16x8*>(VtZ + (size_t)r2 * Ss + t0 + h2 + j * 8);
    }
    __syncthreads();
    // QK: wave computes 64 s-rows x 32 t-cols
    f32x4 acc[4][2] = {};
#pragma unroll
    for (int ks = 0; ks < 2; ks++) {
      bf16x8 bf[2];
#pragma unroll
      for (int nt = 0; nt < 2; nt++)
        bf[nt] = *reinterpret_cast<const bf16x8*>(&Ks[(wt + nt * 16 + ml) * 72 + ks * 32 + q * 8]);
#pragma unroll
      for (int mt = 0; mt < 4; mt++)
#pragma unroll
        for (int nt = 0; nt < 2; nt++)
          acc[mt][nt] = __builtin_amdgcn_mfma_f32_16x16x32_bf16(qa[ks][mt], bf[nt], acc[mt][nt], 0, 0, 0);
    }
    // transform: e1 = exp(S + llic) in (0,1]; A2' = expm1(e1) poly4
#pragma unroll
    for (int nt = 0; nt < 2; nt++) {
      float lcv = lz[t0 + wt + nt * 16 + ml];
#pragma unroll
      for (int mt = 0; mt < 4; mt++)
#pragma unroll
        for (int r = 0; r < 4; r++) {
          float e1 = __expf(acc[mt][nt][r] + lcv);
          float p = e1 * (1.f + e1 * (0.5f + e1 * (0.166666667f + e1 * 0.0416666667f)));
          rsv[mt][r] += p;
          union { float f; u32 u; } cv; cv.f = p;
          A2s[(wsd + mt * 16 + q * 4 + r) * 76 + wt + nt * 16 + ml] =
              (short)((cv.u + 0x8000u) >> 16);
        }
    }
    __syncthreads();
    // PV: wave owns 32 s-rows x 64 d
#pragma unroll
    for (int ks = 0; ks < 2; ks++) {
      bf16x8 af2[2], bv[4];
#pragma unroll
      for (int mt2 = 0; mt2 < 2; mt2++)
        af2[mt2] = *reinterpret_cast<const bf16x8*>(&A2s[(w * 32 + mt2 * 16 + ml) * 76 + ks * 32 + q * 8]);
#pragma unroll
      for (int nt = 0; nt < 4; nt++)
        bv[nt] = *reinterpret_cast<const bf16x8*>(&Vs[(nt * 16 + ml) * 72 + ks * 32 + q * 8]);
#pragma unroll
      for (int mt2 = 0; mt2 < 2; mt2++)
#pragma unroll
        for (int nt = 0; nt < 4; nt++)
          acc2[mt2][nt] = __builtin_amdgcn_mfma_f32_16x16x32_bf16(af2[mt2], bv[nt], acc2[mt2][nt], 0, 0, 0);
    }
  }
  // row sums across the 16 col-lanes
#pragma unroll
  for (int mt = 0; mt < 4; mt++)
#pragma unroll
    for (int r = 0; r < 4; r++) {
      float v = rsv[mt][r];
      v += __shfl_xor(v, 1); v += __shfl_xor(v, 2);
      v += __shfl_xor(v, 4); v += __shfl_xor(v, 8);
      if (ml == 0) rs_s[w & 1][wsd + mt * 16 + q * 4 + r] = v;
    }
  __syncthreads();
  const float* SVz = SV + (size_t)z * Dd;
#pragma unroll
  for (int mt2 = 0; mt2 < 2; mt2++)
#pragma unroll
    for (int r = 0; r < 4; r++) {
      int row = w * 32 + mt2 * 16 + q * 4 + r;
      float inv = 1.f / (2048.f + rs_s[0][row] + rs_s[1][row]);
#pragma unroll
      for (int nt = 0; nt < 4; nt++) {
        float o = (SVz[nt * 16 + ml] + acc2[mt2][nt][r]) * inv;
        Zb[(size_t)(b * Ss + s0 + row) * Ee + h * Dd + nt * 16 + ml] = f2bf(o);
      }
    }
}

// ---------------- ZF (MFMA bf16) + residual: x += Zb@Wz^T + bz; xb refresh ---
__global__ __launch_bounds__(256) void k_zfm(const u16* __restrict__ Zb,
    const u16* __restrict__ Wzb, const float* __restrict__ bzp,
    float* __restrict__ x, u16* __restrict__ xb, int mod) {
  __shared__ short Zs[128][72];
  __shared__ short Ws[128][72];
  int tid = threadIdx.x;
  int coff = blockIdx.x << 7;
  const u16* W = Wzb + (size_t)mod * 256 * 256;
  const float* bias = bzp + mod * Ee;
  int s0 = blockIdx.y * 128;
  int lr = tid >> 1, lc = (tid & 1) << 5;
  int w = tid >> 6, lane = tid & 63, ml = lane & 15, q = lane >> 4;
  int sh = (w >> 1) << 6, th = (w & 1) << 6;
  f32x4 acc[4][4] = {};
  for (int k0 = 0; k0 < 256; k0 += 64) {
#pragma unroll
    for (int hh = 0; hh < 4; hh++) {
      *reinterpret_cast<bf16x8*>(&Zs[lr][lc + hh * 8]) =
          *reinterpret_cast<const bf16x8*>(Zb + (size_t)(s0 + lr) * Ee + k0 + lc + hh * 8);
      *reinterpret_cast<bf16x8*>(&Ws[lr][lc + hh * 8]) =
          *reinterpret_cast<const bf16x8*>(W + (size_t)(coff + lr) * Ee + k0 + lc + hh * 8);
    }
    __syncthreads();
#pragma unroll
    for (int ks = 0; ks < 2; ks++) {
      bf16x8 af[4], bfr[4];
#pragma unroll
      for (int mt = 0; mt < 4; mt++)
        af[mt] = *reinterpret_cast<const bf16x8*>(&Zs[sh + mt * 16 + ml][ks * 32 + q * 8]);
#pragma unroll
      for (int nt = 0; nt < 4; nt++)
        bfr[nt] = *reinterpret_cast<const bf16x8*>(&Ws[th + nt * 16 + ml][ks * 32 + q * 8]);
#pragma unroll
      for (int mt = 0; mt < 4; mt++)
#pragma unroll
        for (int nt = 0; nt < 4; nt++)
          acc[mt][nt] = __builtin_amdgcn_mfma_f32_16x16x32_bf16(af[mt], bfr[nt], acc[mt][nt], 0, 0, 0);
    }
    __syncthreads();
  }
#pragma unroll
  for (int mt = 0; mt < 4; mt++)
#pragma unroll
    for (int nt = 0; nt < 4; nt++)
#pragma unroll
      for (int r = 0; r < 4; r++) {
        int gm = s0 + sh + mt * 16 + q * 4 + r;
        int gn = coff + th + nt * 16 + ml;
        float xv = x[(size_t)gm * Ee + gn] + acc[mt][nt][r] + bias[gn];
        x[(size_t)gm * Ee + gn] = xv;
        xb[(size_t)gm * Ee + gn] = f2bf(xv);
      }
}

// ---------------- final head ----------------
__global__ __launch_bounds__(256) void k_final1(const float* __restrict__ x,
    const float* __restrict__ Wo, float* __restrict__ part) {
  int c = blockIdx.x, l = blockIdx.y, b = blockIdx.z;
  int tid = threadIdx.x;
  const float4* xr = reinterpret_cast<const float4*>(x + (size_t)b * (Ss * Ee) + c * 8192);
  const float4* wr = reinterpret_cast<const float4*>(Wo + (size_t)l * (Ss * Ee) + c * 8192);
  float sum = 0.f;
  for (int i = tid; i < 2048; i += 256) {
    float4 a = xr[i], w = wr[i];
    sum += a.x * w.x + a.y * w.y + a.z * w.z + a.w * w.w;
  }
  __shared__ float red[256];
  red[tid] = sum;
  __syncthreads();
  for (int o = 128; o; o >>= 1) {
    if (tid < o) red[tid] += red[tid + o];
    __syncthreads();
  }
  if (tid == 0) part[((b * 16 + l) << 6) + c] = red[0];
}

__global__ void k_final2(const float* __restrict__ part, const float* __restrict__ bo,
                         float* __restrict__ out) {
  int idx = threadIdx.x;   // 128 = 8*16
  int b = idx >> 4, l = idx & 15;
  float s = 0.f;
  for (int c = 0; c < 64; c++) s += part[((b * 16 + l) << 6) + c];
  s += bo[l];
  out[idx] = 1.f / (1.f + __expf(-s));
}

extern "C" void kernel_launch(void* const* d_in, const int* in_sizes, int n_in,
                              void* d_out, int out_size, void* d_ws, size_t ws_size,
                              hipStream_t stream) {
  const int*   seqs = (const int*)d_in[0];
  const float* emb  = (const float*)d_in[1];
  const float* Wq   = (const float*)d_in[2];
  const float* bq   = (const float*)d_in[3];
  const float* Wk   = (const float*)d_in[4];
  const float* bk   = (const float*)d_in[5];
  const float* Wv   = (const float*)d_in[6];
  const float* bv   = (const float*)d_in[7];
  const float* Wz   = (const float*)d_in[8];
  const float* bz   = (const float*)d_in[9];
  const float* Wo   = (const float*)d_in[10];
  const float* bo   = (const float*)d_in[11];
  float* out = (float*)d_out;
  float* ws  = (float*)d_ws;

  float* x    = ws;                                    // 4,194,304 f
  u16*   xb   = (u16*)(ws + 4194304);
  u16*   Qf   = (u16*)(ws + 6291456);
  u16*   Kf   = (u16*)(ws + 8388608);
  u16*   Vf   = (u16*)(ws + 10485760);
  u16*   Vt   = (u16*)(ws + 12582912);
  u16*   Zb   = (u16*)(ws + 14680064);
  float* SV   = ws + 16777216;                         // 2,048 f
  float* part = ws + 16779264;                         // 8,192 f
  u16*   Wqb  = (u16*)(ws + 16787456);
  u16*   Wkb  = (u16*)(ws + 16852992);
  u16*   Wvb  = (u16*)(ws + 16918528);
  u16*   Wzb  = (u16*)(ws + 16984064);
  float* llic = ws + 17049600;                         // 65,536 f (32 z x 2048)

  k_gather<<<(Bb * Ss * 64) / 256, 256, 0, stream>>>(seqs, emb, x, xb);
  k_w2b<<<131072 / 1024, 256, 0, stream>>>(Wq, Wqb);
  k_w2b<<<131072 / 1024, 256, 0, stream>>>(Wk, Wkb);
  k_w2b<<<131072 / 1024, 256, 0, stream>>>(Wv, Wvb);
  k_w2b<<<131072 / 1024, 256, 0, stream>>>(Wz, Wzb);

  for (int m = 0; m < 2; m++) {
    k_qkvm<<<dim3(6, 128), 256, 0, stream>>>(xb, Wqb, Wkb, Wvb, bq, bk, bv, Qf, Kf, Vf, m);
    k_vt<<<dim3(32, 32), 256, 0, stream>>>(Vf, Vt);
    k_vsum<<<dim3(16, 32), 256, 0, stream>>>(Vt, SV);
    k_csum<<<dim3(16, 32), 256, 0, stream>>>(Qf, Kf, llic);
    k_att<<<dim3(16, 32), 256, 0, stream>>>(Qf, Kf, Vt, llic, SV, Zb);
    k_zfm<<<dim3(2, 128), 256, 0, stream>>>(Zb, Wzb, bz, x, xb, m);
  }

  k_final1<<<dim3(64, 16, 8), 256, 0, stream>>>(x, Wo, part);
  k_final2<<<1, 128, 0, stream>>>(part, bo, out);
}